// Round 3
// baseline (969.148 us; speedup 1.0000x reference)
//
#include <hip/hip_runtime.h>
#include <hip/hip_bf16.h>

// DecoderRNN: attention degenerate (enc seq len == 1 -> awe == gate*features).
// R3: recurrence = persistent plain-launch kernel (32 blocks, ZERO LDS) with a
//     manual device-scope grid barrier (agent atomics + threadfence); Wcomb
//     fragments read from L2 each step. Big GEMM keeps global_load_lds + XCD
//     chunking (R2 gemm2 — validated by the poison-product signature).

#define VV 50257
#define VP 50304   // 393*128
#define TT 20
#define NBLK 32    // recurrence blocks (one per 16-wide jj slice)

typedef __attribute__((ext_vector_type(4))) float f32x4;
typedef __attribute__((ext_vector_type(8))) short bf16x8;

#define MFMA(a,b,c) __builtin_amdgcn_mfma_f32_16x16x32_bf16((a),(b),(c),0,0,0)

__device__ __forceinline__ unsigned short f2bf(float f){
  union { float f; unsigned int u; } v; v.f = f;
  unsigned int u = v.u;
  return (unsigned short)((u + 0x7FFFu + ((u >> 16) & 1u)) >> 16);
}
__device__ __forceinline__ float sigf(float x){ return 1.f/(1.f + expf(-x)); }

__device__ __forceinline__ void gload_lds16(const unsigned short* g, unsigned short* l){
  __builtin_amdgcn_global_load_lds(
      (const __attribute__((address_space(1))) unsigned int*)g,
      (__attribute__((address_space(3))) unsigned int*)l, 16, 0, 0);
}

// device-scope grid barrier: monotonic counter, target = 32*(index+1)
__device__ __forceinline__ void gbar(unsigned int* cnt, unsigned int target){
  __syncthreads();
  if(threadIdx.x == 0){
    __threadfence();   // release: drain stores, L2 writeback (agent scope)
    __hip_atomic_fetch_add(cnt, 1u, __ATOMIC_RELEASE, __HIP_MEMORY_SCOPE_AGENT);
    while(__hip_atomic_load(cnt, __ATOMIC_ACQUIRE, __HIP_MEMORY_SCOPE_AGENT) < target)
      __builtin_amdgcn_s_sleep(2);
    __threadfence();   // acquire: invalidate L1/stale L2 before data reads
  }
  __syncthreads();
}

// ---------- prep kernels ----------

__global__ __launch_bounds__(256) void cvt_weights(const float* __restrict__ Wih,
    const float* __restrict__ Whh, unsigned short* __restrict__ Wcomb,
    unsigned short* __restrict__ We){
  int j = blockIdx.x; int tid = threadIdx.x;
  for(int q=0;q<4;q++){ int k = tid + 256*q;
    float v = (k < 512) ? Whh[j*512 + k] : Wih[j*1024 + k];
    Wcomb[(size_t)j*1024 + k] = f2bf(v); }
  for(int q=0;q<2;q++){ int k = tid + 256*q;
    We[(size_t)j*512 + k] = f2bf(Wih[j*1024 + k]); }
}

// dst[c][r] = bf16(src[r][c]); src f32 [R][C]; dst [Cpad][R]; pad rows zeroed
__global__ __launch_bounds__(256) void transpose_cvt(const float* __restrict__ src,
    unsigned short* __restrict__ dst, int R, int C){
  __shared__ float tile[64][65];
  int c0 = blockIdx.x*64, r0 = blockIdx.y*64;
  int tx = threadIdx.x & 63, ty = threadIdx.x >> 6;
  for(int i=0;i<16;i++){
    int r = ty + i*4; int sc = c0 + tx;
    tile[r][tx] = (sc < C) ? src[(size_t)(r0+r)*C + sc] : 0.f;
  }
  __syncthreads();
  for(int i=0;i<16;i++){
    int cl = ty + i*4;
    dst[(size_t)(c0+cl)*R + r0 + tx] = f2bf(tile[tx][cl]);
  }
}

__global__ __launch_bounds__(128) void build_emb(const float* __restrict__ feat,
    const float* __restrict__ emb, const int* __restrict__ cap,
    unsigned short* __restrict__ EmbMat){
  int m = blockIdx.x; int t = m >> 6, b = m & 63;
  const float* src = (t == 0) ? (feat + b*512) : (emb + (size_t)cap[b*19 + (t-1)]*512);
  for(int q=0;q<4;q++){ int k = threadIdx.x + 128*q;
    EmbMat[(size_t)m*512 + k] = f2bf(src[k]); }
}

__global__ __launch_bounds__(512) void init_hc(const float* __restrict__ feat,
    const float* __restrict__ Whi, const float* __restrict__ bhi,
    const float* __restrict__ Wci, const float* __restrict__ bci,
    unsigned short* __restrict__ x0, float* __restrict__ c){
  int b = blockIdx.x; int j = threadIdx.x;
  float ah = bhi[j], ac = bci[j];
  for(int k=0;k<512;k++){
    float f = feat[b*512 + k];
    ah += f * Whi[k*512 + j];
    ac += f * Wci[k*512 + j];
  }
  x0[b*1024 + j] = f2bf(ah);
  c[b*512 + j] = ac;
}

// ---------- 128x128 NT MFMA GEMM, K=512, global_load_lds staging ----------
// EPIL 0: Cout[m*2048+n] = acc + bias1[n] + bias2[n]
// EPIL 1: out[m*VV+n] = (t<len[b]) ? acc + bias1[n] : 0   (m=b*20+t, guard n<VV)
template<int EPIL>
__global__ __launch_bounds__(256) void gemm2(const unsigned short* __restrict__ Abf,
    const unsigned short* __restrict__ Bbf, const float* __restrict__ bias1,
    const float* __restrict__ bias2, const int* __restrict__ lensp,
    float* __restrict__ Cout, int MT){
  __shared__ __align__(16) unsigned short As[128*64];
  __shared__ __align__(16) unsigned short Bs[128*64];
  // bijective chunked XCD swizzle (m204), m-fastest so one B-tile serves MT m-blocks
  const int nwg = gridDim.x;
  const int id = blockIdx.x;
  const int q = nwg >> 3, rr = nwg & 7;
  const int xcd = id & 7, pos = id >> 3;
  const int work = (xcd < rr) ? (xcd*(q+1) + pos) : (rr*(q+1) + (xcd-rr)*q + pos);
  const int m0 = (work % MT) * 128;
  const int n0 = (work / MT) * 128;
  const int tid = threadIdx.x, lane = tid & 63, w = tid >> 6;
  const int wr = w >> 1, wc = w & 1;
  const int lrow = lane >> 3, lcol = (lane & 7) * 8;

  f32x4 acc[4][4];
#pragma unroll
  for(int i=0;i<4;i++)
#pragma unroll
    for(int j=0;j<4;j++) acc[i][j] = f32x4{0.f,0.f,0.f,0.f};

  for(int k0=0;k0<512;k0+=64){
    __syncthreads();
#pragma unroll
    for(int i=0;i<4;i++){
      int c = w*4 + i;                 // 16 chunks of 8 rows x 64 cols (1 KB each)
      int row = c*8 + lrow;
      gload_lds16(Abf + (size_t)(m0+row)*512 + k0 + lcol, As + c*512);
      gload_lds16(Bbf + (size_t)(n0+row)*512 + k0 + lcol, Bs + c*512);
    }
    asm volatile("s_waitcnt vmcnt(0)" ::: "memory");
    __syncthreads();
#pragma unroll
    for(int kk=0;kk<64;kk+=32){
      bf16x8 af[4], bfv[4];
#pragma unroll
      for(int mf=0;mf<4;mf++)
        af[mf] = *(const bf16x8*)(As + (wr*64 + mf*16 + (lane&15))*64 + kk + (lane>>4)*8);
#pragma unroll
      for(int nf=0;nf<4;nf++)
        bfv[nf] = *(const bf16x8*)(Bs + (wc*64 + nf*16 + (lane&15))*64 + kk + (lane>>4)*8);
#pragma unroll
      for(int mf=0;mf<4;mf++)
#pragma unroll
        for(int nf=0;nf<4;nf++)
          acc[mf][nf] = MFMA(af[mf], bfv[nf], acc[mf][nf]);
    }
  }
#pragma unroll
  for(int mf=0;mf<4;mf++)
#pragma unroll
    for(int nf=0;nf<4;nf++){
      int n = n0 + wc*64 + nf*16 + (lane & 15);
#pragma unroll
      for(int r=0;r<4;r++){
        int m = m0 + wr*64 + mf*16 + (lane>>4)*4 + r;
        float v = acc[mf][nf][r];
        if constexpr (EPIL == 0){
          Cout[(size_t)m*2048 + n] = v + bias1[n] + bias2[n];
        } else {
          if(n < VV){
            int b = m / 20, t = m % 20;
            Cout[(size_t)m*VV + n] = (t < lensp[b]) ? (v + bias1[n]) : 0.f;
          }
        }
      }
    }
}

// ---------- persistent recurrence: all 20 steps, manual grid barrier ----------
// 32 blocks x 256 thr; block owns jj-slice [16*blk, 16*blk+16); wave w owns
// b-rows [16w, 16w+16). Per step:
//   phase1: beta-GEMM + gates-h (K 0..511) -> write awe     -> barrier
//   phase2: gates-awe (K 512..1023) + fused LSTM -> write h -> barrier
// B-fragments read directly from global (Wcomb 4MB = XCD-L2-resident). No LDS.
__global__ __launch_bounds__(256) void recur(
    const unsigned short* __restrict__ Wcomb,  // [2048][1024] bf16
    const unsigned short* __restrict__ Wbt,    // [512][512] bf16 (W_beta^T)
    const float* __restrict__ bbeta,
    const float* __restrict__ feat,            // [64][512] f32
    const float* __restrict__ E,               // [1280][2048] f32
    const float* __restrict__ c0,              // [64][512] f32
    const int* __restrict__ lens,
    unsigned short* __restrict__ x0,           // [64][1024] bf16 (h|awe)
    unsigned short* __restrict__ x1,
    unsigned short* __restrict__ hs,           // [1280][512] bf16
    unsigned int* __restrict__ barcnt){
  const int tid = threadIdx.x;
  const int lane = tid & 63, w = tid >> 6;
  const int l15 = lane & 15, lhi = lane >> 4;
  const int jj0 = blockIdx.x * 16;
  const int jj = jj0 + l15;
  const int arow = w*16 + l15;               // A-frag row (b) for this lane
  const unsigned short* pWb = Wbt   + (size_t)(jj0 + l15)*512;
  const unsigned short* pW0 = Wcomb + (size_t)(0*512 + jj)*1024;
  const unsigned short* pW1 = Wcomb + (size_t)(1*512 + jj)*1024;
  const unsigned short* pW2 = Wcomb + (size_t)(2*512 + jj)*1024;
  const unsigned short* pW3 = Wcomb + (size_t)(3*512 + jj)*1024;

  float c_reg[4], fe[4]; int ln[4];
#pragma unroll
  for(int r=0;r<4;r++){
    int b = w*16 + lhi*4 + r;
    c_reg[r] = c0[b*512 + jj];
    fe[r]    = feat[b*512 + jj];
    ln[r]    = lens[b];
  }
  const float bb = bbeta[jj];

  for(int t=0;t<TT;t++){
    const unsigned short* xc = (t & 1) ? x1 : x0;
    unsigned short* xcw = (unsigned short*)xc;
    unsigned short* xn  = (t & 1) ? x0 : x1;

    f32x4 acca = f32x4{0.f,0.f,0.f,0.f};
    f32x4 accg[4];
#pragma unroll
    for(int i=0;i<4;i++) accg[i] = f32x4{0.f,0.f,0.f,0.f};

    // ---- phase 1: K 0..511 (h part): beta + gates-h
#pragma unroll 4
    for(int kk=0;kk<512;kk+=32){
      int ko = kk + lhi*8;
      bf16x8 af  = *(const bf16x8*)(xc + (size_t)arow*1024 + ko);
      bf16x8 bvb = *(const bf16x8*)(pWb + ko);
      bf16x8 b0  = *(const bf16x8*)(pW0 + ko);
      bf16x8 b1  = *(const bf16x8*)(pW1 + ko);
      bf16x8 b2  = *(const bf16x8*)(pW2 + ko);
      bf16x8 b3  = *(const bf16x8*)(pW3 + ko);
      acca    = MFMA(af, bvb, acca);
      accg[0] = MFMA(af, b0, accg[0]);
      accg[1] = MFMA(af, b1, accg[1]);
      accg[2] = MFMA(af, b2, accg[2]);
      accg[3] = MFMA(af, b3, accg[3]);
    }
#pragma unroll
    for(int r=0;r<4;r++){
      int b = w*16 + lhi*4 + r;
      float g = sigf(acca[r] + bb);
      xcw[b*1024 + 512 + jj] = f2bf(g * fe[r]);
    }
    gbar(barcnt, (unsigned)(t*2+1)*NBLK);

    // ---- phase 2: K 512..1023 (awe part)
#pragma unroll 4
    for(int kk=512;kk<1024;kk+=32){
      int ko = kk + lhi*8;
      bf16x8 af = *(const bf16x8*)(xc + (size_t)arow*1024 + ko);
      bf16x8 b0 = *(const bf16x8*)(pW0 + ko);
      bf16x8 b1 = *(const bf16x8*)(pW1 + ko);
      bf16x8 b2 = *(const bf16x8*)(pW2 + ko);
      bf16x8 b3 = *(const bf16x8*)(pW3 + ko);
      accg[0] = MFMA(af, b0, accg[0]);
      accg[1] = MFMA(af, b1, accg[1]);
      accg[2] = MFMA(af, b2, accg[2]);
      accg[3] = MFMA(af, b3, accg[3]);
    }
    // ---- fused LSTM epilogue
#pragma unroll
    for(int r=0;r<4;r++){
      int b = w*16 + lhi*4 + r;
      size_t eb = ((size_t)(t*64 + b))*2048 + jj;
      float iv = sigf(accg[0][r] + E[eb]);
      float fv = sigf(accg[1][r] + E[eb + 512]);
      float gv = tanhf(accg[2][r] + E[eb + 1024]);
      float ov = sigf(accg[3][r] + E[eb + 1536]);
      float cn = fv*c_reg[r] + iv*gv;
      float hn = ov * tanhf(cn);
      bool valid = t < ln[r];
      if(valid) c_reg[r] = cn;
      hs[((size_t)b*20 + t)*512 + jj] = f2bf(hn);
      xn[b*1024 + jj] = valid ? f2bf(hn) : xc[b*1024 + jj];
    }
    if(t < TT-1) gbar(barcnt, (unsigned)(t*2+2)*NBLK);
  }
}

// ---------- launcher ----------
extern "C" void kernel_launch(void* const* d_in, const int* in_sizes, int n_in,
                              void* d_out, int out_size, void* d_ws, size_t ws_size,
                              hipStream_t stream){
  const float* feat  = (const float*)d_in[0];
  const int*   cap   = (const int*)  d_in[1];
  const int*   lens  = (const int*)  d_in[2];
  const float* emb   = (const float*)d_in[3];
  const float* Wih   = (const float*)d_in[4];
  const float* Whh   = (const float*)d_in[5];
  const float* bih   = (const float*)d_in[6];
  const float* bhh   = (const float*)d_in[7];
  // d_in[8..13]: attention weights -- dead (enc seq len == 1)
  const float* Whi   = (const float*)d_in[14];
  const float* bhi   = (const float*)d_in[15];
  const float* Wci   = (const float*)d_in[16];
  const float* bci   = (const float*)d_in[17];
  const float* Wbeta = (const float*)d_in[18];
  const float* bbeta = (const float*)d_in[19];
  const float* Wfc   = (const float*)d_in[20];
  const float* bfc   = (const float*)d_in[21];
  float* out = (float*)d_out;

  char* ws = (char*)d_ws;
  size_t off = 0;
  auto alloc = [&](size_t bytes)->void*{
    void* p = ws + off; off += (bytes + 1023) & ~(size_t)1023; return p; };
  unsigned short* Wcomb  = (unsigned short*)alloc((size_t)2048*1024*2);
  unsigned short* We     = (unsigned short*)alloc((size_t)2048*512*2);
  unsigned short* Wbt    = (unsigned short*)alloc((size_t)512*512*2);
  unsigned short* Wfct   = (unsigned short*)alloc((size_t)VP*512*2);
  unsigned short* EmbMat = (unsigned short*)alloc((size_t)1280*512*2);
  float*          Emat   = (float*)alloc((size_t)1280*2048*4);
  unsigned short* x0     = (unsigned short*)alloc((size_t)64*1024*2);
  unsigned short* x1     = (unsigned short*)alloc((size_t)64*1024*2);
  float*          cbuf   = (float*)alloc((size_t)64*512*4);
  unsigned short* hs     = (unsigned short*)alloc((size_t)1280*512*2);
  unsigned int*   barcnt = (unsigned int*)alloc(64);

  hipMemsetAsync(barcnt, 0, 64, stream);
  cvt_weights<<<2048, 256, 0, stream>>>(Wih, Whh, Wcomb, We);
  transpose_cvt<<<dim3(8,8),   256, 0, stream>>>(Wbeta, Wbt, 512, 512);
  transpose_cvt<<<dim3(786,8), 256, 0, stream>>>(Wfc,  Wfct, 512, VV);
  build_emb<<<1280, 128, 0, stream>>>(feat, emb, cap, EmbMat);
  init_hc<<<64, 512, 0, stream>>>(feat, Whi, bhi, Wci, bci, x0, cbuf);

  // E = emb-part of gates + b_ih + b_hh: M=1280, N=2048, K=512
  gemm2<0><<<160, 256, 0, stream>>>(EmbMat, We, bih, bhh, nullptr, Emat, 10);

  // persistent recurrence: 20 steps, manual device-scope grid barriers
  recur<<<NBLK, 256, 0, stream>>>(Wcomb, Wbt, bbeta, feat, Emat, cbuf, lens,
                                  x0, x1, hs, barcnt);

  // preds: out[b*20+t][n] = mask ? hs @ Wfc + b_fc : 0 ; M=1280, N=50304, K=512
  gemm2<1><<<3930, 256, 0, stream>>>(hs, Wfct, bfc, nullptr, lens, out, 10);
}

// Round 5
// 919.075 us; speedup vs baseline: 1.0545x; 1.0545x over previous
//
#include <hip/hip_runtime.h>
#include <hip/hip_bf16.h>

// DecoderRNN: attention degenerate (enc seq len == 1 -> awe == gate*features).
// R5 == R4 with the phase-2 weight-offset bug fixed (+1024 -> +512: Wcomb rows
//     are 1024 elements, awe-part is cols [512,1024)).
//     Persistent recurrence, no agent fences: cross-block x=[h|awe] accessed only
//     via sc0/sc1 bypass; barrier = vmcnt(0) -> relaxed agent atomicAdd -> bypass
//     spin. Weights/E stay cached (L2-resident, no invalidates). Wfc transpose
//     runs on recur's extra 6288 blocks.

#define VV 50257
#define VP 50304   // 786*64
#define TT 20
#define NBLK 32    // recurrence blocks (one per 16-wide jj slice)

typedef __attribute__((ext_vector_type(4))) float f32x4;
typedef __attribute__((ext_vector_type(8))) short bf16x8;

#define MFMA(a,b,c) __builtin_amdgcn_mfma_f32_16x16x32_bf16((a),(b),(c),0,0,0)

__device__ __forceinline__ unsigned short f2bf(float f){
  union { float f; unsigned int u; } v; v.f = f;
  unsigned int u = v.u;
  return (unsigned short)((u + 0x7FFFu + ((u >> 16) & 1u)) >> 16);
}
__device__ __forceinline__ float sigf(float x){ return 1.f/(1.f + expf(-x)); }

__device__ __forceinline__ void gload_lds16(const unsigned short* g, unsigned short* l){
  __builtin_amdgcn_global_load_lds(
      (const __attribute__((address_space(1))) unsigned int*)g,
      (__attribute__((address_space(3))) unsigned int*)l, 16, 0, 0);
}

// ---- device-coherent (cross-XCD) bypass accessors: sc0 sc1 = no L1/L2 caching ----
__device__ __forceinline__ void co_load16(bf16x8* d, const unsigned short* p){
  asm volatile("global_load_dwordx4 %0, %1, off sc0 sc1" : "=v"(*d) : "v"(p));
}
__device__ __forceinline__ unsigned short co_load_u16(const unsigned short* p){
  unsigned short r;
  asm volatile("global_load_ushort %0, %1, off sc0 sc1\n\ts_waitcnt vmcnt(0)"
               : "=v"(r) : "v"(p) : "memory");
  return r;
}
__device__ __forceinline__ void co_store2(unsigned short* p, unsigned short v){
  asm volatile("global_store_short %0, %1, off sc0 sc1" :: "v"(p), "v"(v) : "memory");
}
__device__ __forceinline__ unsigned int co_load_u32(const unsigned int* p){
  unsigned int r;
  asm volatile("global_load_dword %0, %1, off sc0 sc1\n\ts_waitcnt vmcnt(0)"
               : "=v"(r) : "v"(p) : "memory");
  return r;
}

// grid barrier among the NBLK recurrence blocks: NO cache maintenance.
__device__ __forceinline__ void gbar(unsigned int* cnt, unsigned int target){
  asm volatile("s_waitcnt vmcnt(0)" ::: "memory");   // per-wave: drain bypass stores
  __syncthreads();
  if(threadIdx.x == 0){
    __hip_atomic_fetch_add(cnt, 1u, __ATOMIC_RELAXED, __HIP_MEMORY_SCOPE_AGENT);
    while(co_load_u32(cnt) < target) __builtin_amdgcn_s_sleep(1);
  }
  __syncthreads();
}

// ---------- prep kernels ----------

__global__ __launch_bounds__(256) void cvt_weights(const float* __restrict__ Wih,
    const float* __restrict__ Whh, unsigned short* __restrict__ Wcomb,
    unsigned short* __restrict__ We){
  int j = blockIdx.x; int tid = threadIdx.x;
  for(int q=0;q<4;q++){ int k = tid + 256*q;
    float v = (k < 512) ? Whh[j*512 + k] : Wih[j*1024 + k];
    Wcomb[(size_t)j*1024 + k] = f2bf(v); }
  for(int q=0;q<2;q++){ int k = tid + 256*q;
    We[(size_t)j*512 + k] = f2bf(Wih[j*1024 + k]); }
}

// dst[c][r] = bf16(src[r][c]); src f32 [R][C]; dst [Cpad][R]
__global__ __launch_bounds__(256) void transpose_cvt(const float* __restrict__ src,
    unsigned short* __restrict__ dst, int R, int C){
  __shared__ float tile[64][65];
  int c0 = blockIdx.x*64, r0 = blockIdx.y*64;
  int tx = threadIdx.x & 63, ty = threadIdx.x >> 6;
  for(int i=0;i<16;i++){
    int r = ty + i*4; int sc = c0 + tx;
    tile[r][tx] = (sc < C) ? src[(size_t)(r0+r)*C + sc] : 0.f;
  }
  __syncthreads();
  for(int i=0;i<16;i++){
    int cl = ty + i*4;
    dst[(size_t)(c0+cl)*R + r0 + tx] = f2bf(tile[tx][cl]);
  }
}

__global__ __launch_bounds__(128) void build_emb(const float* __restrict__ feat,
    const float* __restrict__ emb, const int* __restrict__ cap,
    unsigned short* __restrict__ EmbMat){
  int m = blockIdx.x; int t = m >> 6, b = m & 63;
  const float* src = (t == 0) ? (feat + b*512) : (emb + (size_t)cap[b*19 + (t-1)]*512);
  for(int q=0;q<4;q++){ int k = threadIdx.x + 128*q;
    EmbMat[(size_t)m*512 + k] = f2bf(src[k]); }
}

// h0/c0 init; 16 blocks x 512 thr, 4 b-rows per block (amortize weight reads)
__global__ __launch_bounds__(512) void init_hc(const float* __restrict__ feat,
    const float* __restrict__ Whi, const float* __restrict__ bhi,
    const float* __restrict__ Wci, const float* __restrict__ bci,
    unsigned short* __restrict__ x0, float* __restrict__ c){
  int j = threadIdx.x; int b0 = blockIdx.x*4;
  float ah[4], ac[4];
#pragma unroll
  for(int r=0;r<4;r++){ ah[r] = bhi[j]; ac[r] = bci[j]; }
  for(int k=0;k<512;k++){
    float wh = Whi[k*512 + j], wc = Wci[k*512 + j];
#pragma unroll
    for(int r=0;r<4;r++){
      float f = feat[(b0+r)*512 + k];
      ah[r] += f*wh; ac[r] += f*wc;
    }
  }
#pragma unroll
  for(int r=0;r<4;r++){
    x0[(b0+r)*1024 + j] = f2bf(ah[r]);
    c[(b0+r)*512 + j] = ac[r];
  }
}

// ---------- 128x128 NT MFMA GEMM, K=512, global_load_lds staging ----------
// EPIL 0: E4[((m*512)+col)*4 + gate] = acc + bias1[n] + bias2[n]   (n = gate*512+col)
// EPIL 1: out[m*VV+n] = (t<len[b]) ? acc + bias1[n] : 0  (m=b*20+t; nontemporal)
template<int EPIL>
__global__ __launch_bounds__(256) void gemm2(const unsigned short* __restrict__ Abf,
    const unsigned short* __restrict__ Bbf, const float* __restrict__ bias1,
    const float* __restrict__ bias2, const int* __restrict__ lensp,
    float* __restrict__ Cout, int MT){
  __shared__ __align__(16) unsigned short As[128*64];
  __shared__ __align__(16) unsigned short Bs[128*64];
  const int nwg = gridDim.x;
  const int id = blockIdx.x;
  const int q = nwg >> 3, rr = nwg & 7;
  const int xcd = id & 7, pos = id >> 3;
  const int work = (xcd < rr) ? (xcd*(q+1) + pos) : (rr*(q+1) + (xcd-rr)*q + pos);
  const int m0 = (work % MT) * 128;
  const int n0 = (work / MT) * 128;
  const int tid = threadIdx.x, lane = tid & 63, w = tid >> 6;
  const int wr = w >> 1, wc = w & 1;
  const int lrow = lane >> 3, lcol = (lane & 7) * 8;

  f32x4 acc[4][4];
#pragma unroll
  for(int i=0;i<4;i++)
#pragma unroll
    for(int j=0;j<4;j++) acc[i][j] = f32x4{0.f,0.f,0.f,0.f};

  for(int k0=0;k0<512;k0+=64){
    __syncthreads();
#pragma unroll
    for(int i=0;i<4;i++){
      int c = w*4 + i;
      int row = c*8 + lrow;
      gload_lds16(Abf + (size_t)(m0+row)*512 + k0 + lcol, As + c*512);
      gload_lds16(Bbf + (size_t)(n0+row)*512 + k0 + lcol, Bs + c*512);
    }
    asm volatile("s_waitcnt vmcnt(0)" ::: "memory");
    __syncthreads();
#pragma unroll
    for(int kk=0;kk<64;kk+=32){
      bf16x8 af[4], bfv[4];
#pragma unroll
      for(int mf=0;mf<4;mf++)
        af[mf] = *(const bf16x8*)(As + (wr*64 + mf*16 + (lane&15))*64 + kk + (lane>>4)*8);
#pragma unroll
      for(int nf=0;nf<4;nf++)
        bfv[nf] = *(const bf16x8*)(Bs + (wc*64 + nf*16 + (lane&15))*64 + kk + (lane>>4)*8);
#pragma unroll
      for(int mf=0;mf<4;mf++)
#pragma unroll
        for(int nf=0;nf<4;nf++)
          acc[mf][nf] = MFMA(af[mf], bfv[nf], acc[mf][nf]);
    }
  }
#pragma unroll
  for(int mf=0;mf<4;mf++)
#pragma unroll
    for(int nf=0;nf<4;nf++){
      int n = n0 + wc*64 + nf*16 + (lane & 15);
#pragma unroll
      for(int r=0;r<4;r++){
        int m = m0 + wr*64 + mf*16 + (lane>>4)*4 + r;
        float v = acc[mf][nf][r];
        if constexpr (EPIL == 0){
          int gate = n >> 9, col = n & 511;
          Cout[((size_t)m*512 + col)*4 + gate] = v + bias1[n] + bias2[n];
        } else {
          if(n < VV){
            int b = m / 20, t = m % 20;
            float o = (t < lensp[b]) ? (v + bias1[n]) : 0.f;
            __builtin_nontemporal_store(o, &Cout[(size_t)m*VV + n]);
          }
        }
      }
    }
}

// ---------- persistent recurrence (+ embedded Wfc transpose on extra blocks) ----------
// Blocks [0,NBLK): recurrence; block owns jj-slice [16*blk,16*blk+16); wave w owns
// b-rows [16w,16w+16). Single x buffer [64][1024] = [h|awe], ALL accesses bypass.
// Blocks [NBLK, NBLK+786*8): transpose Wfc f32 [512][VV] -> Wfct bf16 [VP][512].
__global__ __launch_bounds__(256) void recur(
    const unsigned short* __restrict__ Wcomb,  // [2048][1024] bf16
    const unsigned short* __restrict__ Wbt,    // [512][512] bf16 (W_beta^T)
    const float* __restrict__ bbeta,
    const float* __restrict__ feat,            // [64][512] f32
    const float* __restrict__ E4,              // [1280][512][4] f32 gate-minor
    const float* __restrict__ c0,
    const int* __restrict__ lens,
    unsigned short* x,                         // [64][1024] (h|awe)
    unsigned short* __restrict__ hs,           // [1280][512] bf16
    unsigned int* barcnt,
    const float* __restrict__ Wfc, unsigned short* __restrict__ Wfct){
  __shared__ float tile[64][65];

  if(blockIdx.x >= NBLK){
    // ---- embedded transpose (runs concurrently with the recurrence) ----
    int tb = blockIdx.x - NBLK;
    int c0t = (tb % 786)*64, r0 = (tb / 786)*64;
    int tx = threadIdx.x & 63, ty = threadIdx.x >> 6;
    for(int i=0;i<16;i++){
      int r = ty + i*4; int sc = c0t + tx;
      tile[r][tx] = (sc < VV) ? Wfc[(size_t)(r0+r)*VV + sc] : 0.f;
    }
    __syncthreads();
    for(int i=0;i<16;i++){
      int cl = ty + i*4;
      Wfct[(size_t)(c0t+cl)*512 + r0 + tx] = f2bf(tile[tx][cl]);
    }
    return;
  }

  const int tid = threadIdx.x;
  const int lane = tid & 63, w = tid >> 6;
  const int l15 = lane & 15, lhi = lane >> 4;
  const int jj0 = blockIdx.x * 16;
  const int jj = jj0 + l15;
  const int arow = w*16 + l15;
  const unsigned short* pA  = x + (size_t)arow*1024 + lhi*8;
  const unsigned short* pWb = Wbt   + (size_t)(jj0 + l15)*512 + lhi*8;
  const unsigned short* pW0 = Wcomb + (size_t)(0*512 + jj)*1024 + lhi*8;
  const unsigned short* pW1 = Wcomb + (size_t)(1*512 + jj)*1024 + lhi*8;
  const unsigned short* pW2 = Wcomb + (size_t)(2*512 + jj)*1024 + lhi*8;
  const unsigned short* pW3 = Wcomb + (size_t)(3*512 + jj)*1024 + lhi*8;

  float c_reg[4], fe[4]; int ln[4]; unsigned short hold[4];
#pragma unroll
  for(int r=0;r<4;r++){
    int b = w*16 + lhi*4 + r;
    c_reg[r] = c0[b*512 + jj];
    fe[r]    = feat[b*512 + jj];
    ln[r]    = lens[b];
    hold[r]  = co_load_u16(x + b*1024 + jj);
  }
  const float bb = bbeta[jj];

  for(int t=0;t<TT;t++){
    // ---- phase 1: K 0..511 (h part): beta + gates-h
    bf16x8 a[16];
#pragma unroll
    for(int i=0;i<16;i++) co_load16(&a[i], pA + i*32);
    asm volatile("s_waitcnt vmcnt(0)" ::: "memory");
    __builtin_amdgcn_sched_barrier(0);

    f32x4 acca = f32x4{0.f,0.f,0.f,0.f};
    f32x4 accg[4];
#pragma unroll
    for(int i=0;i<4;i++) accg[i] = f32x4{0.f,0.f,0.f,0.f};
#pragma unroll
    for(int i=0;i<16;i++){
      bf16x8 bvb = *(const bf16x8*)(pWb + i*32);
      bf16x8 b0  = *(const bf16x8*)(pW0 + i*32);
      bf16x8 b1  = *(const bf16x8*)(pW1 + i*32);
      bf16x8 b2  = *(const bf16x8*)(pW2 + i*32);
      bf16x8 b3  = *(const bf16x8*)(pW3 + i*32);
      acca    = MFMA(a[i], bvb, acca);
      accg[0] = MFMA(a[i], b0, accg[0]);
      accg[1] = MFMA(a[i], b1, accg[1]);
      accg[2] = MFMA(a[i], b2, accg[2]);
      accg[3] = MFMA(a[i], b3, accg[3]);
    }
#pragma unroll
    for(int r=0;r<4;r++){
      int b = w*16 + lhi*4 + r;
      float g = sigf(acca[r] + bb);
      co_store2(x + b*1024 + 512 + jj, f2bf(g * fe[r]));
    }
    gbar(barcnt, (unsigned)(t*2+1)*NBLK);

    // ---- phase 2: K 512..1023 (awe part); Wcomb awe cols are [512,1024)
#pragma unroll
    for(int i=0;i<16;i++) co_load16(&a[i], pA + 512 + i*32);
    asm volatile("s_waitcnt vmcnt(0)" ::: "memory");
    __builtin_amdgcn_sched_barrier(0);
#pragma unroll
    for(int i=0;i<16;i++){
      bf16x8 b0 = *(const bf16x8*)(pW0 + 512 + i*32);   // FIX: was +1024 (OOB row)
      bf16x8 b1 = *(const bf16x8*)(pW1 + 512 + i*32);
      bf16x8 b2 = *(const bf16x8*)(pW2 + 512 + i*32);
      bf16x8 b3 = *(const bf16x8*)(pW3 + 512 + i*32);
      accg[0] = MFMA(a[i], b0, accg[0]);
      accg[1] = MFMA(a[i], b1, accg[1]);
      accg[2] = MFMA(a[i], b2, accg[2]);
      accg[3] = MFMA(a[i], b3, accg[3]);
    }
    // ---- fused LSTM epilogue
#pragma unroll
    for(int r=0;r<4;r++){
      int b = w*16 + lhi*4 + r;
      f32x4 e4 = *(const f32x4*)(E4 + (((size_t)(t*64 + b))*512 + jj)*4);
      float iv = sigf(accg[0][r] + e4[0]);
      float fv = sigf(accg[1][r] + e4[1]);
      float gv = tanhf(accg[2][r] + e4[2]);
      float ov = sigf(accg[3][r] + e4[3]);
      float cn = fv*c_reg[r] + iv*gv;
      float hn = ov * tanhf(cn);
      bool valid = t < ln[r];
      if(valid) c_reg[r] = cn;
      unsigned short hb = valid ? f2bf(hn) : hold[r];
      hold[r] = hb;
      hs[((size_t)b*20 + t)*512 + jj] = hb;
      co_store2(x + b*1024 + jj, hb);
    }
    if(t < TT-1) gbar(barcnt, (unsigned)(t*2+2)*NBLK);
  }
}

// ---------- launcher ----------
extern "C" void kernel_launch(void* const* d_in, const int* in_sizes, int n_in,
                              void* d_out, int out_size, void* d_ws, size_t ws_size,
                              hipStream_t stream){
  const float* feat  = (const float*)d_in[0];
  const int*   cap   = (const int*)  d_in[1];
  const int*   lens  = (const int*)  d_in[2];
  const float* emb   = (const float*)d_in[3];
  const float* Wih   = (const float*)d_in[4];
  const float* Whh   = (const float*)d_in[5];
  const float* bih   = (const float*)d_in[6];
  const float* bhh   = (const float*)d_in[7];
  // d_in[8..13]: attention weights -- dead (enc seq len == 1)
  const float* Whi   = (const float*)d_in[14];
  const float* bhi   = (const float*)d_in[15];
  const float* Wci   = (const float*)d_in[16];
  const float* bci   = (const float*)d_in[17];
  const float* Wbeta = (const float*)d_in[18];
  const float* bbeta = (const float*)d_in[19];
  const float* Wfc   = (const float*)d_in[20];
  const float* bfc   = (const float*)d_in[21];
  float* out = (float*)d_out;

  char* ws = (char*)d_ws;
  size_t off = 0;
  auto alloc = [&](size_t bytes)->void*{
    void* p = ws + off; off += (bytes + 1023) & ~(size_t)1023; return p; };
  unsigned short* Wcomb  = (unsigned short*)alloc((size_t)2048*1024*2);
  unsigned short* We     = (unsigned short*)alloc((size_t)2048*512*2);
  unsigned short* Wbt    = (unsigned short*)alloc((size_t)512*512*2);
  unsigned short* Wfct   = (unsigned short*)alloc((size_t)VP*512*2);
  unsigned short* EmbMat = (unsigned short*)alloc((size_t)1280*512*2);
  float*          E4     = (float*)alloc((size_t)1280*2048*4);
  unsigned short* x0     = (unsigned short*)alloc((size_t)64*1024*2);
  float*          cbuf   = (float*)alloc((size_t)64*512*4);
  unsigned short* hs     = (unsigned short*)alloc((size_t)1280*512*2);
  unsigned int*   barcnt = (unsigned int*)alloc(64);

  hipMemsetAsync(barcnt, 0, 64, stream);
  cvt_weights<<<2048, 256, 0, stream>>>(Wih, Whh, Wcomb, We);
  transpose_cvt<<<dim3(8,8), 256, 0, stream>>>(Wbeta, Wbt, 512, 512);
  build_emb<<<1280, 128, 0, stream>>>(feat, emb, cap, EmbMat);
  init_hc<<<16, 512, 0, stream>>>(feat, Whi, bhi, Wci, bci, x0, cbuf);

  // E4 = emb-part of gates + b_ih + b_hh (gate-minor layout): M=1280, N=2048, K=512
  gemm2<0><<<160, 256, 0, stream>>>(EmbMat, We, bih, bhh, nullptr, E4, 10);

  // persistent recurrence (blocks 0..31) + embedded Wfc transpose (blocks 32..6319)
  recur<<<NBLK + 786*8, 256, 0, stream>>>(Wcomb, Wbt, bbeta, feat, E4, cbuf, lens,
                                          x0, hs, barcnt, Wfc, Wfct);

  // preds: out[b*20+t][n] = mask ? hs @ Wfc + b_fc : 0 ; M=1280, N=50304, K=512
  gemm2<1><<<3930, 256, 0, stream>>>(hs, Wfct, bfc, nullptr, lens, out, 10);
}